// Round 19
// baseline (91.935 us; speedup 1.0000x reference)
//
#include <hip/hip_runtime.h>
#include <hip/hip_bf16.h>

typedef unsigned short u16;
typedef unsigned long long u64;
typedef __attribute__((ext_vector_type(4))) float f32x4;
typedef __attribute__((ext_vector_type(8))) short bf16x8;

#define IN_F   4096
#define OUT_F  4096
#define BATCH  512

#define BM 128
#define BN 128
#define BK 64
#define KSPLIT 4
#define KC (IN_F / KSPLIT)     // 1024
#define NSTEPS (KC / BK)       // 16
#define NTILES ((BATCH / BM) * (OUT_F / BN))   // 128

#define NXCD    8
#define NB      512            // coarse buckets, 8 rows each
#define CHUNK   2048           // entries per bucket_scatter block
#define LCAP    16             // LDS bucket cap (mean 4)
#define SEGCAP  1024           // per (xcd,bucket) seg cap (mean 390, +32 sigma)
#define WCAP    161            // per (row,wave) list cap (mean 97.7, +6.4 sigma)
#define SCAP2   256            // block-local stash
#define GOVFCAP (1024*1024)
#define NCTR    (NXCD * NB + 2 + NTILES)   // gcur + govf_cnt + spare + tilectr

__device__ inline u16 f2bf(float f) {
    __hip_bfloat16 h = __float2bfloat16(f);   // RNE
    u16 u; __builtin_memcpy(&u, &h, 2); return u;
}

// conv_x + counter clear (incl. tilectr for the fused-gemm epilogue).
__global__ __launch_bounds__(256) void conv_x(const float* __restrict__ x,
                                              u16* __restrict__ xbf,
                                              int* __restrict__ ctrs) {
    const int tid = threadIdx.x;
    if (blockIdx.x == 0) {
        for (int j = tid; j < NCTR; j += 256) ctrs[j] = 0;
    }
    int i = blockIdx.x * 256 + tid;
    float4 v = ((const float4*)x)[i];
    ushort4 o;
    o.x = f2bf(v.x); o.y = f2bf(v.y); o.z = f2bf(v.z); o.w = f2bf(v.w);
    ((ushort4*)xbf)[i] = o;
}

// Phase 1: LDS-aggregated coarse binning, weight inlined. (frozen, r15 form)
// bin entry: (i<<32)|(rl<<28)|(col<<16)|wbf, rl = row&7.
// govf: (i<<40)|(row<<28)|(col<<16)|wbf.
__global__ __launch_bounds__(256) void bucket_scatter(const int* __restrict__ row,
                                                      const int* __restrict__ col,
                                                      const float* __restrict__ w,
                                                      int* __restrict__ gcur,
                                                      u64* __restrict__ bins,
                                                      int* __restrict__ govf_cnt,
                                                      u64* __restrict__ govf, int nnz) {
    __shared__ u64 lbin[NB][LCAP];   // 64 KB
    __shared__ int lcur[NB];         // 2 KB
    const int xcd = __builtin_amdgcn_s_getreg(20 | (3 << 11)) & (NXCD - 1);
    const int tid = threadIdx.x;
    lcur[tid] = 0;
    lcur[tid + 256] = 0;
    __syncthreads();

    int base = blockIdx.x * CHUNK + tid * 8;
    if (base + 8 <= nnz) {
        int4 r0 = ((const int4*)(row + base))[0];
        int4 r1 = ((const int4*)(row + base))[1];
        int4 c0 = ((const int4*)(col + base))[0];
        int4 c1 = ((const int4*)(col + base))[1];
        float4 w0 = ((const float4*)(w + base))[0];
        float4 w1 = ((const float4*)(w + base))[1];
        int rs[8] = {r0.x, r0.y, r0.z, r0.w, r1.x, r1.y, r1.z, r1.w};
        int cs[8] = {c0.x, c0.y, c0.z, c0.w, c1.x, c1.y, c1.z, c1.w};
        float wsv[8] = {w0.x, w0.y, w0.z, w0.w, w1.x, w1.y, w1.z, w1.w};
#pragma unroll
        for (int j = 0; j < 8; j++) {
            int rr = rs[j], cc = cs[j], i = base + j;
            u64 wb = (u64)f2bf(wsv[j]);
            int bk = rr >> 3;
            int p = atomicAdd(&lcur[bk], 1);
            if (p < LCAP) {
                lbin[bk][p] = ((u64)i << 32) | ((u64)(rr & 7) << 28) | ((u64)cc << 16) | wb;
            } else {
                int o = atomicAdd(govf_cnt, 1);
                if (o < GOVFCAP) govf[o] = ((u64)i << 40) | ((u64)rr << 28) | ((u64)cc << 16) | wb;
            }
        }
    } else {
        int e = nnz < base + 8 ? nnz : base + 8;
        for (int i = base; i < e; i++) {
            int rr = row[i], cc = col[i];
            u64 wb = (u64)f2bf(w[i]);
            int bk = rr >> 3;
            int p = atomicAdd(&lcur[bk], 1);
            if (p < LCAP) {
                lbin[bk][p] = ((u64)i << 32) | ((u64)(rr & 7) << 28) | ((u64)cc << 16) | wb;
            } else {
                int o = atomicAdd(govf_cnt, 1);
                if (o < GOVFCAP) govf[o] = ((u64)i << 40) | ((u64)rr << 28) | ((u64)cc << 16) | wb;
            }
        }
    }
    __syncthreads();

    // flush: thread t owns buckets t and t+256
#pragma unroll
    for (int bb = 0; bb < 2; bb++) {
        int bk = tid + bb * 256;
        int cnt = lcur[bk];
        if (cnt > LCAP) cnt = LCAP;
        if (cnt > 0) {
            int gb = (xcd << 9) | bk;
            int b0 = atomicAdd(&gcur[gb], cnt);
            u64* seg = bins + (size_t)gb * SEGCAP;
            for (int k = 0; k < cnt; k++) {
                u64 e = lbin[bk][k];
                int p = b0 + k;
                if (p < SEGCAP) {
                    seg[p] = e;
                } else {
                    int rr = (bk << 3) | ((int)(e >> 28) & 7);
                    int o = atomicAdd(govf_cnt, 1);
                    if (o < GOVFCAP) govf[o] = ((e >> 32) << 40) | ((u64)rr << 28) | (e & 0x0FFFFFFF);
                }
            }
        }
    }
}

// split_build over 8-row buckets. ROUND-19: per-wave list segments +
// per-wave cursors. r14's counter showed 11.6M LDS bank-conflict cycles
// (~45% of runtime): lists[8][640] u64 put every list base on bank 0
// (5120B stride ≡ 0 mod 128B) -> a wave's 64 route-writes into 8 lists
// hit the same bank pair ~8-way; and 256 threads shared 8 cursors (~32
// same-address atomics serialized per round). Now lists[8][4][161]:
// segment stride 1288B ≡ 2 mod 32 dwords spreads 32 segments over 16
// banks, and each wave owns its cursors (contention /4, intra-wave only).
// LDS ~75.5KB -> still 2 blocks/CU. Stats: Poisson(97.7) per (row,wave),
// WCAP=161=+6.4sigma; stash/govf fallback keeps correctness cap-free.
__global__ __launch_bounds__(256) void split_build(const int* __restrict__ gcur,
                                                   const u64* __restrict__ bins,
                                                   const int* __restrict__ govf_cnt,
                                                   const u64* __restrict__ govf,
                                                   u16* __restrict__ Wbf) {
    __shared__ u64 lists[8][4][WCAP]; // 41.2 KB
    __shared__ u64 stash[SCAP2];      // 2 KB
    __shared__ u64 aux[IN_F];         // 32 KB
    __shared__ int lcurW[8][4];
    __shared__ int scnt;
    const int bucket = blockIdx.x;
    const int tid = threadIdx.x;
    const int wv  = tid >> 6;
    if (tid < 32) lcurW[tid >> 2][tid & 3] = 0;
    if (tid == 0) scnt = 0;
    __syncthreads();

    // route: read the 8 per-XCD segs once, into per-wave segments
#pragma unroll
    for (int xcd = 0; xcd < NXCD; xcd++) {
        int gb = (xcd << 9) | bucket;
        int cnt = gcur[gb];
        if (cnt > SEGCAP) cnt = SEGCAP;
        const u64* seg = bins + (size_t)gb * SEGCAP;
        for (int k = tid; k < cnt; k += 256) {
            u64 e = seg[k];
            int rl = (int)(e >> 28) & 7;
            int p = atomicAdd(&lcurW[rl][wv], 1);
            if (p < WCAP) lists[rl][wv][p] = e;
            else { int s = atomicAdd(&scnt, 1); if (s < SCAP2) stash[s] = e; }
        }
    }
    // rare overflow entries from scatter
    int ovfn = *govf_cnt;
    if (ovfn > GOVFCAP) ovfn = GOVFCAP;
    for (int k = tid; k < ovfn; k += 256) {
        u64 e = govf[k];
        int rr = (int)(e >> 28) & 4095;
        if ((rr >> 3) == bucket) {
            u64 e2 = ((e >> 40) << 32) | ((u64)(rr & 7) << 28) | (e & 0x0FFFFFFF);
            int rl = rr & 7;
            int p = atomicAdd(&lcurW[rl][wv], 1);
            if (p < WCAP) lists[rl][wv][p] = e2;
            else { int s = atomicAdd(&scnt, 1); if (s < SCAP2) stash[s] = e2; }
        }
    }
    __syncthreads();
    const int sn = scnt > SCAP2 ? SCAP2 : scnt;

    // resolve + emit each of the 8 rows, all from LDS
    for (int rl = 0; rl < 8; rl++) {
#pragma unroll
        for (int j = 0; j < 8; j++)
            ((ulonglong2*)aux)[tid * 8 + j] = (ulonglong2){0ull, 0ull};
        __syncthreads();

#pragma unroll
        for (int w = 0; w < 4; w++) {
            int cnt = lcurW[rl][w];
            if (cnt > WCAP) cnt = WCAP;
            for (int k = tid; k < cnt; k += 256) {
                u64 e = lists[rl][w][k];
                atomicMax(&aux[(int)(e >> 16) & 4095], ((e >> 32) << 16) | (e & 0xFFFF));
            }
        }
        for (int k = tid; k < sn; k += 256) {
            u64 e = stash[k];
            if (((int)(e >> 28) & 7) == rl)
                atomicMax(&aux[(int)(e >> 16) & 4095], ((e >> 32) << 16) | (e & 0xFFFF));
        }
        __syncthreads();

        int rowg = (bucket << 3) | rl;
        int base = tid * 16;
        ushort4 o[4];
#pragma unroll
        for (int j = 0; j < 16; j++)
            ((u16*)o)[j] = (u16)(aux[base + j] & 0xFFFF);
        uint4* dst = (uint4*)(Wbf + (size_t)rowg * IN_F + base);
        dst[0] = ((const uint4*)o)[0];
        dst[1] = ((const uint4*)o)[1];
        __syncthreads();
    }
}

// GEMM — main loop byte-identical to r13/r15; fence-free same-XCD
// last-arriver reduction (r17, verified). (frozen)
__global__ __launch_bounds__(256) void gemm_fused(const u16* __restrict__ A,
                                                  const u16* __restrict__ B,
                                                  const float* __restrict__ bias,
                                                  u16* __restrict__ part,
                                                  int* __restrict__ tilectr,
                                                  float* __restrict__ y) {
    __shared__ u16 As[2][BM * BK];   // 2 x 16 KB
    __shared__ u16 Bs[2][BN * BK];   // 2 x 16 KB => 64 KB
    __shared__ int done_s;
    const int L   = blockIdx.x;
    const int xx  = L & 7;
    const int rst = L >> 3;
    const int m   = rst & 3;
    const int g   = ((rst >> 2) << 3) | xx;   // g%8==L%8 -> XCD-affine B panel; kc-peers same XCD
    const int n   = g & 31;
    const int kc  = g >> 5;
    const int m0  = m * BM;
    const int n0  = n * BN;
    const int kt0 = kc * KC;

    const int tid  = threadIdx.x;
    const int lane = tid & 63;
    const int wave = tid >> 6;
    const int wm = wave >> 1, wn = wave & 1;   // 2x2 waves, wave tile 64x64
    const int r15 = lane & 15, khi = lane >> 4;

    const u16* srcA[4]; const u16* srcB[4]; int dstO[4];
#pragma unroll
    for (int it = 0; it < 4; it++) {
        int o = tid * 16 + it * 4096;
        int rr = o >> 7, lblk = (o >> 4) & 7;
        srcA[it] = A + (size_t)(m0 + rr) * IN_F + kt0 + ((lblk ^ (rr & 7)) << 3);
        srcB[it] = B + (size_t)(n0 + rr) * IN_F + kt0 + ((lblk ^ (rr & 7)) << 3);
        dstO[it] = o >> 1;
    }

#define STAGE(buf, kk)                                                               \
    do {                                                                             \
        _Pragma("unroll")                                                            \
        for (int it = 0; it < 4; it++)                                               \
            __builtin_amdgcn_global_load_lds(                                        \
                (const __attribute__((address_space(1))) void*)(srcA[it] + (kk)),    \
                (__attribute__((address_space(3))) void*)(&As[buf][dstO[it]]),       \
                16, 0, 0);                                                           \
        _Pragma("unroll")                                                            \
        for (int it = 0; it < 4; it++)                                               \
            __builtin_amdgcn_global_load_lds(                                        \
                (const __attribute__((address_space(1))) void*)(srcB[it] + (kk)),    \
                (__attribute__((address_space(3))) void*)(&Bs[buf][dstO[it]]),       \
                16, 0, 0);                                                           \
    } while (0)

    f32x4 acc[4][4];
#pragma unroll
    for (int mi = 0; mi < 4; mi++)
#pragma unroll
        for (int nj = 0; nj < 4; nj++) acc[mi][nj] = (f32x4){0.f, 0.f, 0.f, 0.f};

    STAGE(0, 0);   // 8 loads outstanding; no drain here

    for (int t = 0; t < NSTEPS; ++t) {
        const int cur = t & 1;
        if (t + 1 < NSTEPS) {
            STAGE(cur ^ 1, (t + 1) * BK);                      // 8 more in flight
            asm volatile("s_waitcnt vmcnt(8)" ::: "memory");   // tile t landed
        } else {
            asm volatile("s_waitcnt vmcnt(0)" ::: "memory");
        }
        __builtin_amdgcn_s_barrier();

        const char* as = (const char*)&As[cur][0];
        const char* bs = (const char*)&Bs[cur][0];
#pragma unroll
        for (int ks = 0; ks < 2; ks++) {
            bf16x8 a[4], b[4];
#pragma unroll
            for (int mi = 0; mi < 4; mi++) {
                int rowi = wm * 64 + mi * 16 + r15;
                a[mi] = *(const bf16x8*)(as + rowi * 128 + (((ks * 4 + khi) ^ (rowi & 7)) << 4));
            }
#pragma unroll
            for (int nj = 0; nj < 4; nj++) {
                int rowi = wn * 64 + nj * 16 + r15;
                b[nj] = *(const bf16x8*)(bs + rowi * 128 + (((ks * 4 + khi) ^ (rowi & 7)) << 4));
            }
#pragma unroll
            for (int mi = 0; mi < 4; mi++)
#pragma unroll
                for (int nj = 0; nj < 4; nj++)
                    acc[mi][nj] = __builtin_amdgcn_mfma_f32_16x16x32_bf16(a[mi], b[nj], acc[mi][nj], 0, 0, 0);
        }
        __builtin_amdgcn_s_barrier();
    }
#undef STAGE

    // partial store (bf16, r13)
    u16* P = part + (size_t)kc * BATCH * OUT_F;
#pragma unroll
    for (int nj = 0; nj < 4; nj++) {
        int colg = n0 + wn * 64 + nj * 16 + r15;
#pragma unroll
        for (int mi = 0; mi < 4; mi++) {
#pragma unroll
            for (int j = 0; j < 4; j++) {
                int rowg = m0 + wm * 64 + mi * 16 + khi * 4 + j;
                P[(size_t)rowg * OUT_F + colg] = f2bf(acc[mi][nj][j]);
            }
        }
    }

    // fence-free last-arriver: stores committed to (same-XCD) L2, no cache ops
    asm volatile("s_waitcnt vmcnt(0)" ::: "memory");
    __syncthreads();
    if (tid == 0) {
        int old = atomicAdd(&tilectr[m * 32 + n], 1);
        done_s = (old == KSPLIT - 1) ? 1 : 0;
    }
    __syncthreads();
    if (done_s) {
        // reduce this 128x128 tile: 2048 bf16x8-groups, 8 per thread (L2 hits)
#pragma unroll
        for (int j = 0; j < 8; j++) {
            int gi = j * 256 + tid;
            int r  = gi >> 4;          // 16 groups per row
            int c8 = gi & 15;
            size_t addr = (size_t)(m0 + r) * OUT_F + n0 + c8 * 8;
            float s[8];
#pragma unroll
            for (int e = 0; e < 8; e++) s[e] = 0.f;
#pragma unroll
            for (int k = 0; k < KSPLIT; k++) {
                const u16* p = part + (size_t)k * BATCH * OUT_F + addr;
                ushort4 v0 = ((const ushort4*)p)[0];
                ushort4 v1 = ((const ushort4*)p)[1];
                unsigned vv[8] = {v0.x, v0.y, v0.z, v0.w, v1.x, v1.y, v1.z, v1.w};
#pragma unroll
                for (int e = 0; e < 8; e++) {
                    unsigned u = vv[e] << 16;
                    float f; __builtin_memcpy(&f, &u, 4);
                    s[e] += f;
                }
            }
            int col = n0 + c8 * 8;
            f32x4 b0 = *(const f32x4*)&bias[col];
            f32x4 b1 = *(const f32x4*)&bias[col + 4];
            f32x4 o0 = {s[0] + b0[0], s[1] + b0[1], s[2] + b0[2], s[3] + b0[3]};
            f32x4 o1 = {s[4] + b1[0], s[5] + b1[1], s[6] + b1[2], s[7] + b1[3]};
            ((f32x4*)(y + addr))[0] = o0;
            ((f32x4*)(y + addr))[1] = o1;
        }
    }
}

extern "C" void kernel_launch(void* const* d_in, const int* in_sizes, int n_in,
                              void* d_out, int out_size, void* d_ws, size_t ws_size,
                              hipStream_t stream) {
    const float* x    = (const float*)d_in[0];
    const float* w1d  = (const float*)d_in[1];
    const float* bias = (const float*)d_in[2];
    const int*   row  = (const int*)d_in[3];
    const int*   col  = (const int*)d_in[4];
    const int nnz = in_sizes[1];

    char* ws        = (char*)d_ws;
    u64*  bins      = (u64*)ws;                             // 32 MB [0,32) — dead after split_build
    u16*  part      = (u16*)ws;                             // 16 MB [0,16) — overlays bins (bf16 partials)
    int*  gcur      = (int*)(ws + ((size_t)32 << 20));      // 16 KB + cnts + tilectr = NCTR ints
    int*  govf_cnt  = gcur + NXCD * NB;
    int*  tilectr   = govf_cnt + 2;                         // 128 ints
    u64*  govf      = (u64*)(ws + ((size_t)33 << 20));      // 8 MB  [33,41)
    u16*  Wbf       = (u16*)(ws + ((size_t)64 << 20));      // 32 MB [64,96)
    u16*  xbf       = (u16*)(ws + ((size_t)96 << 20));      // 4 MB  [96,100)
    float* y        = (float*)d_out;

    conv_x<<<(BATCH * IN_F / 4) / 256, 256, 0, stream>>>(x, xbf, gcur);
    int nblk = (nnz + CHUNK - 1) / CHUNK;
    bucket_scatter<<<nblk, 256, 0, stream>>>(row, col, w1d, gcur, bins, govf_cnt, govf, nnz);
    split_build<<<NB, 256, 0, stream>>>(gcur, bins, govf_cnt, govf, Wbf);
    gemm_fused<<<512, 256, 0, stream>>>(xbf, Wbf, bias, part, tilectr, y);
}

// Round 20
// 88.651 us; speedup vs baseline: 1.0370x; 1.0370x over previous
//
#include <hip/hip_runtime.h>
#include <hip/hip_bf16.h>

typedef unsigned short u16;
typedef unsigned long long u64;
typedef __attribute__((ext_vector_type(4))) float f32x4;
typedef __attribute__((ext_vector_type(8))) short bf16x8;

#define IN_F   4096
#define OUT_F  4096
#define BATCH  512

#define BM 128
#define BN 128
#define BK 64
#define KSPLIT 4
#define KC (IN_F / KSPLIT)     // 1024
#define NSTEPS (KC / BK)       // 16
#define NTILES ((BATCH / BM) * (OUT_F / BN))   // 128

#define NXCD    8
#define NB      512            // coarse buckets, 8 rows each
#define CHUNK   2048           // entries per bucket_scatter block
#define LCAP    16             // LDS bucket cap (mean 4)
#define SEGCAP  1024           // per (xcd,bucket) seg cap (mean 390, +32 sigma)
#define RCAP    640            // per-row list cap (mean 390, +12.7 sigma)
#define SCAP2   256            // block-local stash
#define GOVFCAP (1024*1024)
#define NCTR    (NXCD * NB + 2 + NTILES)   // gcur + govf_cnt + spare + tilectr

__device__ inline u16 f2bf(float f) {
    __hip_bfloat16 h = __float2bfloat16(f);   // RNE
    u16 u; __builtin_memcpy(&u, &h, 2); return u;
}

// conv_x + counter clear (incl. tilectr for the fused-gemm epilogue).
__global__ __launch_bounds__(256) void conv_x(const float* __restrict__ x,
                                              u16* __restrict__ xbf,
                                              int* __restrict__ ctrs) {
    const int tid = threadIdx.x;
    if (blockIdx.x == 0) {
        for (int j = tid; j < NCTR; j += 256) ctrs[j] = 0;
    }
    int i = blockIdx.x * 256 + tid;
    float4 v = ((const float4*)x)[i];
    ushort4 o;
    o.x = f2bf(v.x); o.y = f2bf(v.y); o.z = f2bf(v.z); o.w = f2bf(v.w);
    ((ushort4*)xbf)[i] = o;
}

// Phase 1: LDS-aggregated coarse binning, weight inlined. (frozen, r15 form)
// bin entry: (i<<32)|(rl<<28)|(col<<16)|wbf, rl = row&7.
// govf: (i<<40)|(row<<28)|(col<<16)|wbf.
__global__ __launch_bounds__(256) void bucket_scatter(const int* __restrict__ row,
                                                      const int* __restrict__ col,
                                                      const float* __restrict__ w,
                                                      int* __restrict__ gcur,
                                                      u64* __restrict__ bins,
                                                      int* __restrict__ govf_cnt,
                                                      u64* __restrict__ govf, int nnz) {
    __shared__ u64 lbin[NB][LCAP];   // 64 KB
    __shared__ int lcur[NB];         // 2 KB
    const int xcd = __builtin_amdgcn_s_getreg(20 | (3 << 11)) & (NXCD - 1);
    const int tid = threadIdx.x;
    lcur[tid] = 0;
    lcur[tid + 256] = 0;
    __syncthreads();

    int base = blockIdx.x * CHUNK + tid * 8;
    if (base + 8 <= nnz) {
        int4 r0 = ((const int4*)(row + base))[0];
        int4 r1 = ((const int4*)(row + base))[1];
        int4 c0 = ((const int4*)(col + base))[0];
        int4 c1 = ((const int4*)(col + base))[1];
        float4 w0 = ((const float4*)(w + base))[0];
        float4 w1 = ((const float4*)(w + base))[1];
        int rs[8] = {r0.x, r0.y, r0.z, r0.w, r1.x, r1.y, r1.z, r1.w};
        int cs[8] = {c0.x, c0.y, c0.z, c0.w, c1.x, c1.y, c1.z, c1.w};
        float wsv[8] = {w0.x, w0.y, w0.z, w0.w, w1.x, w1.y, w1.z, w1.w};
#pragma unroll
        for (int j = 0; j < 8; j++) {
            int rr = rs[j], cc = cs[j], i = base + j;
            u64 wb = (u64)f2bf(wsv[j]);
            int bk = rr >> 3;
            int p = atomicAdd(&lcur[bk], 1);
            if (p < LCAP) {
                lbin[bk][p] = ((u64)i << 32) | ((u64)(rr & 7) << 28) | ((u64)cc << 16) | wb;
            } else {
                int o = atomicAdd(govf_cnt, 1);
                if (o < GOVFCAP) govf[o] = ((u64)i << 40) | ((u64)rr << 28) | ((u64)cc << 16) | wb;
            }
        }
    } else {
        int e = nnz < base + 8 ? nnz : base + 8;
        for (int i = base; i < e; i++) {
            int rr = row[i], cc = col[i];
            u64 wb = (u64)f2bf(w[i]);
            int bk = rr >> 3;
            int p = atomicAdd(&lcur[bk], 1);
            if (p < LCAP) {
                lbin[bk][p] = ((u64)i << 32) | ((u64)(rr & 7) << 28) | ((u64)cc << 16) | wb;
            } else {
                int o = atomicAdd(govf_cnt, 1);
                if (o < GOVFCAP) govf[o] = ((u64)i << 40) | ((u64)rr << 28) | ((u64)cc << 16) | wb;
            }
        }
    }
    __syncthreads();

    // flush: thread t owns buckets t and t+256
#pragma unroll
    for (int bb = 0; bb < 2; bb++) {
        int bk = tid + bb * 256;
        int cnt = lcur[bk];
        if (cnt > LCAP) cnt = LCAP;
        if (cnt > 0) {
            int gb = (xcd << 9) | bk;
            int b0 = atomicAdd(&gcur[gb], cnt);
            u64* seg = bins + (size_t)gb * SEGCAP;
            for (int k = 0; k < cnt; k++) {
                u64 e = lbin[bk][k];
                int p = b0 + k;
                if (p < SEGCAP) {
                    seg[p] = e;
                } else {
                    int rr = (bk << 3) | ((int)(e >> 28) & 7);
                    int o = atomicAdd(govf_cnt, 1);
                    if (o < GOVFCAP) govf[o] = ((e >> 32) << 40) | ((u64)rr << 28) | (e & 0x0FFFFFFF);
                }
            }
        }
    }
}

// split_build over 8-row buckets: 512 blocks, ~74KB LDS -> 2 blocks/CU.
// Route the 8 segs once into 8 per-row LDS lists, then resolve each row
// in-place (atomicMax(aux[col], (i<<16)|wbf), order-independent), emit.
// (r17 best-measured form; r18 affinity remap and r19 per-wave segments
// both measured neutral and are reverted.)
__global__ __launch_bounds__(256) void split_build(const int* __restrict__ gcur,
                                                   const u64* __restrict__ bins,
                                                   const int* __restrict__ govf_cnt,
                                                   const u64* __restrict__ govf,
                                                   u16* __restrict__ Wbf) {
    __shared__ u64 lists[8][RCAP];    // 40 KB
    __shared__ u64 stash[SCAP2];      // 2 KB
    __shared__ u64 aux[IN_F];         // 32 KB
    __shared__ int lcur[8];
    __shared__ int scnt;
    const int bucket = blockIdx.x;
    const int tid = threadIdx.x;
    if (tid < 8) lcur[tid] = 0;
    if (tid == 0) scnt = 0;
    __syncthreads();

#pragma unroll
    for (int xcd = 0; xcd < NXCD; xcd++) {
        int gb = (xcd << 9) | bucket;
        int cnt = gcur[gb];
        if (cnt > SEGCAP) cnt = SEGCAP;
        const u64* seg = bins + (size_t)gb * SEGCAP;
        for (int k = tid; k < cnt; k += 256) {
            u64 e = seg[k];
            int rl = (int)(e >> 28) & 7;
            int p = atomicAdd(&lcur[rl], 1);
            if (p < RCAP) lists[rl][p] = e;
            else { int s = atomicAdd(&scnt, 1); if (s < SCAP2) stash[s] = e; }
        }
    }
    int ovfn = *govf_cnt;
    if (ovfn > GOVFCAP) ovfn = GOVFCAP;
    for (int k = tid; k < ovfn; k += 256) {
        u64 e = govf[k];
        int rr = (int)(e >> 28) & 4095;
        if ((rr >> 3) == bucket) {
            u64 e2 = ((e >> 40) << 32) | ((u64)(rr & 7) << 28) | (e & 0x0FFFFFFF);
            int rl = rr & 7;
            int p = atomicAdd(&lcur[rl], 1);
            if (p < RCAP) lists[rl][p] = e2;
            else { int s = atomicAdd(&scnt, 1); if (s < SCAP2) stash[s] = e2; }
        }
    }
    __syncthreads();
    const int sn = scnt > SCAP2 ? SCAP2 : scnt;

    for (int rl = 0; rl < 8; rl++) {
#pragma unroll
        for (int j = 0; j < 8; j++)
            ((ulonglong2*)aux)[tid * 8 + j] = (ulonglong2){0ull, 0ull};
        __syncthreads();

        int cnt = lcur[rl];
        if (cnt > RCAP) cnt = RCAP;
        for (int k = tid; k < cnt; k += 256) {
            u64 e = lists[rl][k];
            atomicMax(&aux[(int)(e >> 16) & 4095], ((e >> 32) << 16) | (e & 0xFFFF));
        }
        for (int k = tid; k < sn; k += 256) {
            u64 e = stash[k];
            if (((int)(e >> 28) & 7) == rl)
                atomicMax(&aux[(int)(e >> 16) & 4095], ((e >> 32) << 16) | (e & 0xFFFF));
        }
        __syncthreads();

        int rowg = (bucket << 3) | rl;
        int base = tid * 16;
        ushort4 o[4];
#pragma unroll
        for (int j = 0; j < 16; j++)
            ((u16*)o)[j] = (u16)(aux[base + j] & 0xFFFF);
        uint4* dst = (uint4*)(Wbf + (size_t)rowg * IN_F + base);
        dst[0] = ((const uint4*)o)[0];
        dst[1] = ((const uint4*)o)[1];
        __syncthreads();
    }
}

// GEMM — main loop byte-identical to r13/r15; fence-free same-XCD
// last-arriver reduction (r17, verified). (frozen)
__global__ __launch_bounds__(256) void gemm_fused(const u16* __restrict__ A,
                                                  const u16* __restrict__ B,
                                                  const float* __restrict__ bias,
                                                  u16* __restrict__ part,
                                                  int* __restrict__ tilectr,
                                                  float* __restrict__ y) {
    __shared__ u16 As[2][BM * BK];   // 2 x 16 KB
    __shared__ u16 Bs[2][BN * BK];   // 2 x 16 KB => 64 KB
    __shared__ int done_s;
    const int L   = blockIdx.x;
    const int xx  = L & 7;
    const int rst = L >> 3;
    const int m   = rst & 3;
    const int g   = ((rst >> 2) << 3) | xx;   // g%8==L%8 -> XCD-affine B panel; kc-peers same XCD
    const int n   = g & 31;
    const int kc  = g >> 5;
    const int m0  = m * BM;
    const int n0  = n * BN;
    const int kt0 = kc * KC;

    const int tid  = threadIdx.x;
    const int lane = tid & 63;
    const int wave = tid >> 6;
    const int wm = wave >> 1, wn = wave & 1;   // 2x2 waves, wave tile 64x64
    const int r15 = lane & 15, khi = lane >> 4;

    const u16* srcA[4]; const u16* srcB[4]; int dstO[4];
#pragma unroll
    for (int it = 0; it < 4; it++) {
        int o = tid * 16 + it * 4096;
        int rr = o >> 7, lblk = (o >> 4) & 7;
        srcA[it] = A + (size_t)(m0 + rr) * IN_F + kt0 + ((lblk ^ (rr & 7)) << 3);
        srcB[it] = B + (size_t)(n0 + rr) * IN_F + kt0 + ((lblk ^ (rr & 7)) << 3);
        dstO[it] = o >> 1;
    }

#define STAGE(buf, kk)                                                               \
    do {                                                                             \
        _Pragma("unroll")                                                            \
        for (int it = 0; it < 4; it++)                                               \
            __builtin_amdgcn_global_load_lds(                                        \
                (const __attribute__((address_space(1))) void*)(srcA[it] + (kk)),    \
                (__attribute__((address_space(3))) void*)(&As[buf][dstO[it]]),       \
                16, 0, 0);                                                           \
        _Pragma("unroll")                                                            \
        for (int it = 0; it < 4; it++)                                               \
            __builtin_amdgcn_global_load_lds(                                        \
                (const __attribute__((address_space(1))) void*)(srcB[it] + (kk)),    \
                (__attribute__((address_space(3))) void*)(&Bs[buf][dstO[it]]),       \
                16, 0, 0);                                                           \
    } while (0)

    f32x4 acc[4][4];
#pragma unroll
    for (int mi = 0; mi < 4; mi++)
#pragma unroll
        for (int nj = 0; nj < 4; nj++) acc[mi][nj] = (f32x4){0.f, 0.f, 0.f, 0.f};

    STAGE(0, 0);   // 8 loads outstanding; no drain here

    for (int t = 0; t < NSTEPS; ++t) {
        const int cur = t & 1;
        if (t + 1 < NSTEPS) {
            STAGE(cur ^ 1, (t + 1) * BK);                      // 8 more in flight
            asm volatile("s_waitcnt vmcnt(8)" ::: "memory");   // tile t landed
        } else {
            asm volatile("s_waitcnt vmcnt(0)" ::: "memory");
        }
        __builtin_amdgcn_s_barrier();

        const char* as = (const char*)&As[cur][0];
        const char* bs = (const char*)&Bs[cur][0];
#pragma unroll
        for (int ks = 0; ks < 2; ks++) {
            bf16x8 a[4], b[4];
#pragma unroll
            for (int mi = 0; mi < 4; mi++) {
                int rowi = wm * 64 + mi * 16 + r15;
                a[mi] = *(const bf16x8*)(as + rowi * 128 + (((ks * 4 + khi) ^ (rowi & 7)) << 4));
            }
#pragma unroll
            for (int nj = 0; nj < 4; nj++) {
                int rowi = wn * 64 + nj * 16 + r15;
                b[nj] = *(const bf16x8*)(bs + rowi * 128 + (((ks * 4 + khi) ^ (rowi & 7)) << 4));
            }
#pragma unroll
            for (int mi = 0; mi < 4; mi++)
#pragma unroll
                for (int nj = 0; nj < 4; nj++)
                    acc[mi][nj] = __builtin_amdgcn_mfma_f32_16x16x32_bf16(a[mi], b[nj], acc[mi][nj], 0, 0, 0);
        }
        __builtin_amdgcn_s_barrier();
    }
#undef STAGE

    // partial store (bf16, r13)
    u16* P = part + (size_t)kc * BATCH * OUT_F;
#pragma unroll
    for (int nj = 0; nj < 4; nj++) {
        int colg = n0 + wn * 64 + nj * 16 + r15;
#pragma unroll
        for (int mi = 0; mi < 4; mi++) {
#pragma unroll
            for (int j = 0; j < 4; j++) {
                int rowg = m0 + wm * 64 + mi * 16 + khi * 4 + j;
                P[(size_t)rowg * OUT_F + colg] = f2bf(acc[mi][nj][j]);
            }
        }
    }

    // fence-free last-arriver: stores committed to (same-XCD) L2, no cache ops
    asm volatile("s_waitcnt vmcnt(0)" ::: "memory");
    __syncthreads();
    if (tid == 0) {
        int old = atomicAdd(&tilectr[m * 32 + n], 1);
        done_s = (old == KSPLIT - 1) ? 1 : 0;
    }
    __syncthreads();
    if (done_s) {
        // reduce this 128x128 tile: 2048 bf16x8-groups, 8 per thread (L2 hits)
#pragma unroll
        for (int j = 0; j < 8; j++) {
            int gi = j * 256 + tid;
            int r  = gi >> 4;          // 16 groups per row
            int c8 = gi & 15;
            size_t addr = (size_t)(m0 + r) * OUT_F + n0 + c8 * 8;
            float s[8];
#pragma unroll
            for (int e = 0; e < 8; e++) s[e] = 0.f;
#pragma unroll
            for (int k = 0; k < KSPLIT; k++) {
                const u16* p = part + (size_t)k * BATCH * OUT_F + addr;
                ushort4 v0 = ((const ushort4*)p)[0];
                ushort4 v1 = ((const ushort4*)p)[1];
                unsigned vv[8] = {v0.x, v0.y, v0.z, v0.w, v1.x, v1.y, v1.z, v1.w};
#pragma unroll
                for (int e = 0; e < 8; e++) {
                    unsigned u = vv[e] << 16;
                    float f; __builtin_memcpy(&f, &u, 4);
                    s[e] += f;
                }
            }
            int col = n0 + c8 * 8;
            f32x4 b0 = *(const f32x4*)&bias[col];
            f32x4 b1 = *(const f32x4*)&bias[col + 4];
            f32x4 o0 = {s[0] + b0[0], s[1] + b0[1], s[2] + b0[2], s[3] + b0[3]};
            f32x4 o1 = {s[4] + b1[0], s[5] + b1[1], s[6] + b1[2], s[7] + b1[3]};
            ((f32x4*)(y + addr))[0] = o0;
            ((f32x4*)(y + addr))[1] = o1;
        }
    }
}

extern "C" void kernel_launch(void* const* d_in, const int* in_sizes, int n_in,
                              void* d_out, int out_size, void* d_ws, size_t ws_size,
                              hipStream_t stream) {
    const float* x    = (const float*)d_in[0];
    const float* w1d  = (const float*)d_in[1];
    const float* bias = (const float*)d_in[2];
    const int*   row  = (const int*)d_in[3];
    const int*   col  = (const int*)d_in[4];
    const int nnz = in_sizes[1];

    char* ws        = (char*)d_ws;
    u64*  bins      = (u64*)ws;                             // 32 MB [0,32) — dead after split_build
    u16*  part      = (u16*)ws;                             // 16 MB [0,16) — overlays bins (bf16 partials)
    int*  gcur      = (int*)(ws + ((size_t)32 << 20));      // 16 KB + cnts + tilectr = NCTR ints
    int*  govf_cnt  = gcur + NXCD * NB;
    int*  tilectr   = govf_cnt + 2;                         // 128 ints
    u64*  govf      = (u64*)(ws + ((size_t)33 << 20));      // 8 MB  [33,41)
    u16*  Wbf       = (u16*)(ws + ((size_t)64 << 20));      // 32 MB [64,96)
    u16*  xbf       = (u16*)(ws + ((size_t)96 << 20));      // 4 MB  [96,100)
    float* y        = (float*)d_out;

    conv_x<<<(BATCH * IN_F / 4) / 256, 256, 0, stream>>>(x, xbf, gcur);
    int nblk = (nnz + CHUNK - 1) / CHUNK;
    bucket_scatter<<<nblk, 256, 0, stream>>>(row, col, w1d, gcur, bins, govf_cnt, govf, nnz);
    split_build<<<NB, 256, 0, stream>>>(gcur, bins, govf_cnt, govf, Wbf);
    gemm_fused<<<512, 256, 0, stream>>>(xbf, Wbf, bias, part, tilectr, y);
}